// Round 6
// baseline (65.749 us; speedup 1.0000x reference)
//
#include <hip/hip_runtime.h>
#include <hip/hip_bf16.h>
#include <hip/hip_fp16.h>
#include <math.h>

#define D_MODEL 512
#define N_PEAKS 500
#define BATCH   1024
#define BLOCK   256

// out[b][2k]   = sum_n w * sin(idx * omega_k)
// out[b][2k+1] = sum_n w * cos(idx * omega_k)
// idx = ceil(loc*10); omega_k = exp(2k * -ln(1e4)/512); pe row 0 zeroed.
//
// R6: R2-R5 showed the kernel is bound by the 262M v_sin/v_cos ops (trans
// pipe ~1/8-rate wave64, blocks issue; occupancy/pipelining changes were all
// neutral). This version has ZERO trans ops in the loop: sin(2*pi*f) with
// f=fract(rev) in [0,1) is computed as -P(u), u=2f-1, where P ~= sin(pi*u)
// is a degree-9 odd Chebyshev-economized polynomial evaluated in PACKED f16
// (v_pk_fma_f16, full rate, sin-arg in .x / cos-arg in .y of one __half2).
// f16 poly error ~2e-3/term -> absmax ~0.5 over 500 terms, threshold 3.6.
__global__ __launch_bounds__(BLOCK)
void SpectrumEncoding_84164179132426_kernel(const float* __restrict__ loc,
                                            const float* __restrict__ inten,
                                            float* __restrict__ out) {
    __shared__ float2 s_iw[N_PEAKS];   // {idxf, -w (masked; minus folds -P)}

    const int b = blockIdx.x;
    const int t = threadIdx.x;

    for (int n = t; n < N_PEAKS; n += BLOCK) {
        float l    = loc[b * N_PEAKS + n];
        float idxf = ceilf(l * 10.0f);          // matches jnp.ceil(loc*10)
        float w    = inten[b * N_PEAKS + n];
        s_iw[n] = make_float2(idxf, (idxf == 0.0f) ? 0.0f : -w);
    }
    __syncthreads();

    // omega_k / (2*pi), f64 once per thread for table-grade precision.
    const double cd = -log(10000.0) / (double)D_MODEL;
    const float wk = (float)(exp((double)(2 * t) * cd) / (2.0 * M_PI));

    // sin(pi*u) on [-1,1], odd deg-9, Chebyshev-truncated (err ~6e-6 in f32):
    const __half2 C1 = __float2half2_rn( 3.1415038f);
    const __half2 C3 = __float2half2_rn(-5.1662827f);
    const __half2 C5 = __float2half2_rn( 2.5425620f);
    const __half2 C7 = __float2half2_rn(-0.5817718f);
    const __half2 C9 = __float2half2_rn( 0.0639939f);
    const __half2 TWO  = __float2half2_rn(2.0f);
    const __half2 NONE = __float2half2_rn(-1.0f);

    float acc_s = 0.0f, acc_c = 0.0f;

#pragma unroll 4
    for (int n = 0; n < N_PEAKS; ++n) {
        const float2 iw   = s_iw[n];                      // broadcast ds_read_b64
        const float  revs = iw.x * wk;                    // sin angle (revs)
        const float  revc = fmaf(iw.x, wk, 0.25f);        // cos = sin(+1/4 rev)
        const float  f0   = __builtin_amdgcn_fractf(revs);
        const float  f1   = __builtin_amdgcn_fractf(revc);
        const __half2 h   = __floats2half2_rn(f0, f1);    // v_cvt_pkrtz pack
        const __half2 u   = __hfma2(h, TWO, NONE);        // u = 2f-1 in [-1,1)
        const __half2 u2  = __hmul2(u, u);
        __half2 p = __hfma2(u2, C9, C7);                  // Horner, packed
        p = __hfma2(p, u2, C5);
        p = __hfma2(p, u2, C3);
        p = __hfma2(p, u2, C1);
        p = __hmul2(p, u);                                // P(u) ~= sin(pi*u)
        // sin(2*pi*f) = -P(u); iw.y already holds -w.
        acc_s = fmaf(iw.y, __low2float(p),  acc_s);
        acc_c = fmaf(iw.y, __high2float(p), acc_c);
    }

    *(float2*)(out + b * D_MODEL + 2 * t) = make_float2(acc_s, acc_c);
}

extern "C" void kernel_launch(void* const* d_in, const int* in_sizes, int n_in,
                              void* d_out, int out_size, void* d_ws, size_t ws_size,
                              hipStream_t stream) {
    const float* loc   = (const float*)d_in[0];   // [1024, 500] f32
    const float* inten = (const float*)d_in[1];   // [1024, 500] f32
    // d_in[2] (pe table) intentionally unused: recomputed analytically.
    float*       out   = (float*)d_out;           // [1024, 512] f32

    SpectrumEncoding_84164179132426_kernel<<<BATCH, BLOCK, 0, stream>>>(loc, inten, out);
}

// Round 7
// 43.192 us; speedup vs baseline: 1.5222x; 1.5222x over previous
//
#include <hip/hip_runtime.h>
#include <hip/hip_bf16.h>
#include <math.h>

#define D_MODEL 512
#define N_PEAKS 500
#define BATCH   1024
#define BLOCK   256
#define TBITS   12
#define TSIZE   (1 << TBITS)        // 4096-entry cis table, 32 KB LDS

// out[b][2k]   = sum_n w * sin(idx * omega_k)
// out[b][2k+1] = sum_n w * cos(idx * omega_k)
// idx = ceil(loc*10) in [0,30000]; omega_k = exp(2k * -ln(1e4)/512); pe row 0
// zeroed -> mask idx==0.
//
// R7: R2-R6 established the kernel is VALU-ISSUE bound (~40 cyc/iter-wave,
// dominated by v_sin+v_cos at 1/8 rate; occupancy and pipelining changes were
// null; f16 poly regressed). This version has no per-iter trans and ~12 VALU
// cyc/iter: the angle is computed in 32-bit modular fixed-point —
//   P_k = round(frac(omega_k/2pi) * 2^32)     (exact per-thread constant)
//   x   = idx * P_k (mod 2^32)                (EXACT fractional angle, err<2e-5 rad)
//   j   = top 12 bits of x (rounded)          -> LDS cis-table lookup
// Per iter: v_mul_lo_u32 + add + 2 shifts + ds_read_b64 (gather) + 2 fma.
// Table quantization pi/4096 = 7.7e-4/term -> absmax ~0.3 vs threshold 3.6.
// Random-lane LDS gather has ~4-way avg bank conflicts (~1.6x, acceptable).
__global__ __launch_bounds__(BLOCK)
void SpectrumEncoding_84164179132426_kernel(const float* __restrict__ loc,
                                            const float* __restrict__ inten,
                                            float* __restrict__ out) {
    __shared__ float2 s_cis[TSIZE];    // (sin, cos) of 2*pi*j/TSIZE
    __shared__ uint2  s_iw[N_PEAKS];   // {idx as uint, w bits (masked)}

    const int b = blockIdx.x;
    const int t = threadIdx.x;

    // Fill cis table (16 entries/thread, precise ocml sinf/cosf).
    for (int j = t; j < TSIZE; j += BLOCK) {
        float a = (float)j * (6.28318530717958647693f / (float)TSIZE);
        s_cis[j] = make_float2(sinf(a), cosf(a));
    }

    // Stage peaks: integer index + masked weight.
    for (int n = t; n < N_PEAKS; n += BLOCK) {
        float l    = loc[b * N_PEAKS + n];
        float idxf = ceilf(l * 10.0f);          // matches jnp.ceil(loc*10)
        float w    = inten[b * N_PEAKS + n];
        unsigned int idx = (unsigned int)idxf;
        s_iw[n] = make_uint2(idx, __float_as_uint(idx == 0u ? 0.0f : w));
    }
    __syncthreads();

    // P_k = round(frac(omega_k / 2pi) * 2^32), f64 once per thread.
    const double cd = -log(10000.0) / (double)D_MODEL;
    const double fk = exp((double)(2 * t) * cd) / (2.0 * M_PI);  // in (0, 0.16]
    const unsigned int Pk = (unsigned int)llrint(fk * 4294967296.0);

    float acc_s = 0.0f, acc_c = 0.0f;

#pragma unroll 4
    for (int n = 0; n < N_PEAKS; ++n) {
        const uint2 iw = s_iw[n];                     // broadcast ds_read_b64
        const unsigned int x = iw.x * Pk;             // frac(idx*f_k) in 0.32 fixed pt
        const unsigned int j = (x + (1u << (31 - TBITS))) >> (32 - TBITS);
        const float2 sc = s_cis[j];                   // gathered ds_read_b64
        const float  w  = __uint_as_float(iw.y);
        acc_s = fmaf(w, sc.x, acc_s);
        acc_c = fmaf(w, sc.y, acc_c);
    }

    *(float2*)(out + b * D_MODEL + 2 * t) = make_float2(acc_s, acc_c);
}

extern "C" void kernel_launch(void* const* d_in, const int* in_sizes, int n_in,
                              void* d_out, int out_size, void* d_ws, size_t ws_size,
                              hipStream_t stream) {
    const float* loc   = (const float*)d_in[0];   // [1024, 500] f32
    const float* inten = (const float*)d_in[1];   // [1024, 500] f32
    // d_in[2] (pe table) intentionally unused: recomputed analytically.
    float*       out   = (float*)d_out;           // [1024, 512] f32

    SpectrumEncoding_84164179132426_kernel<<<BATCH, BLOCK, 0, stream>>>(loc, inten, out);
}